// Round 9
// baseline (193.808 us; speedup 1.0000x reference)
//
#include <hip/hip_runtime.h>

// CTC batch loss (keras ctc_batch_cost), B=256, T=512, C=256, U=64.
// Producer/consumer wave specialization (this round): one block of 2 waves
// per batch. Wave 1 (producer) owns the entire memory path: stages each
// time-row (1 KB) via one coalesced global_load_lds dwordx4 into a 4-deep
// LDS ring (counted vmcnt waits, never 0 in steady state), then gathers
// row[label] / row[255] and packs them as float2 into a 2-phase compact
// buffer pk[2][16][64]. Wave 0 (consumer) runs the serial recurrence and
// issues NO VMEM in the loop: barrier -> 16 conflict-free ds_read_b64 ->
// lgkm fence -> 16 steps. All DMA/vmcnt/gather-conflict stalls move off
// the serial wave onto a parallel SIMD.
//
// Sync (lag-1, race-free): both waves execute exactly 33 s_barriers.
//   producer iter c: [vmcnt; PACK(c); STAGE(c+3); lgkm-flush] barrier
//   consumer iter c: [c>=1: read pk[(c-1)&1]; COMP(c-1)] barrier
// consumer work(c) reads pk[c&1] while producer work(c+1) writes
// pk[(c+1)&1] (disjoint); pk[x] is reused only after the reader's barrier.
// rows WAR is producer-local (PACK(c-1) lgkm-drained before STAGE(c+3)
// overwrites rows[(c-1)%4]). Numerics identical to the verified r3-r7
// kernels (same recurrence, same rescale cadence).

constexpr int B = 256, T = 512, C = 256, U = 64;
constexpr int CH = 16;   // time-steps per chunk
constexpr int NBUF = 4;  // LDS row-ring buffers (64 KB)
#define EPSF 1e-7f

typedef float f2 __attribute__((ext_vector_type(2)));

__device__ __forceinline__ float dpp_wave_shr1(float x) {
    // alpha[2l-1]: previous lane's a_odd; lane 0 gets 0 (bound_ctrl).
    return __int_as_float(__builtin_amdgcn_update_dpp(
        0, __float_as_int(x), 0x138, 0xf, 0xf, true));
}

#define DPPMAX(ctrl)                                                      \
    {                                                                     \
        float x_ = __int_as_float(__builtin_amdgcn_update_dpp(            \
            0, __float_as_int(m_), (ctrl), 0xf, 0xf, true));              \
        m_ = fmaxf(m_, x_);                                               \
    }

#define RESCALE()                                                         \
    {                                                                     \
        float m_ = fmaxf(fmaxf(a_even, a_odd), a_top);                    \
        DPPMAX(0x111) DPPMAX(0x112) DPPMAX(0x114) DPPMAX(0x118)           \
        DPPMAX(0x142) DPPMAX(0x143)                                       \
        const float mx_ = __int_as_float(                                 \
            __builtin_amdgcn_readlane(__float_as_int(m_), 63));           \
        int e_ = (__float_as_int(mx_) >> 23) & 0xff;                      \
        int k_ = 187 - e_;                                                \
        k_ = k_ > 127 ? 127 : k_;                                         \
        const float s_ = __int_as_float((k_ + 127) << 23);                \
        a_even *= s_; a_odd *= s_; a_top *= s_;                           \
        esum += k_;                                                       \
    }

// Producer: 16 coalesced row loads (1 KB each, one instr per row) for chunk
// cc into rows[cc % NBUF]. Per-lane global src; wave-uniform LDS dest (HW
// writes lane l at dest + 16*l = linear row copy).
#define STAGE(cc)                                                          \
    {                                                                      \
        const int cs_ = (cc);                                              \
        float* lbase_ = &rows[cs_ % NBUF][0][0];                           \
        _Pragma("unroll")                                                  \
        for (int i = 0; i < CH; ++i) {                                     \
            int t = 1 + cs_ * CH + i;                                      \
            t = t < T ? t : T - 1;                                         \
            const float* g_ = rowp + (size_t)t * C + (lane << 2);          \
            __builtin_amdgcn_global_load_lds(                              \
                (const __attribute__((address_space(1))) void*)g_,         \
                (__attribute__((address_space(3))) void*)(lbase_ + i * C), \
                16, 0, 0);                                                 \
        }                                                                  \
    }

#define DSR(dst, addr, OS)                                                 \
    asm volatile("ds_read_b32 %0, %1 offset:" OS                           \
                 : "=v"(dst) : "v"(addr));

#define DSR64(dst, addr, OS)                                               \
    asm volatile("ds_read_b64 %0, %1 offset:" OS                           \
                 : "=v"(dst) : "v"(addr));

// Producer: gather chunk cc's 32 values from the row ring and pack into
// pk[cc & 1] as float2{lab, blk} at [i][lane] (ds_write_b64, 512 B row
// stride -> conflict-free).
#define PACK(cc)                                                           \
    {                                                                      \
        const int cp_ = (cc);                                              \
        float(*row_)[C] = rows[cp_ % NBUF];                                \
        const unsigned labA_ = (unsigned)(size_t)                          \
            (__attribute__((address_space(3))) void*)&row_[0][label];      \
        const unsigned blkA_ = (unsigned)(size_t)                          \
            (__attribute__((address_space(3))) void*)&row_[0][C - 1];      \
        DSR(lv[0],  labA_, "0")     DSR(lv[1],  labA_, "1024")             \
        DSR(lv[2],  labA_, "2048")  DSR(lv[3],  labA_, "3072")             \
        DSR(lv[4],  labA_, "4096")  DSR(lv[5],  labA_, "5120")             \
        DSR(lv[6],  labA_, "6144")  DSR(lv[7],  labA_, "7168")             \
        DSR(lv[8],  labA_, "8192")  DSR(lv[9],  labA_, "9216")             \
        DSR(lv[10], labA_, "10240") DSR(lv[11], labA_, "11264")            \
        DSR(lv[12], labA_, "12288") DSR(lv[13], labA_, "13312")            \
        DSR(lv[14], labA_, "14336") DSR(lv[15], labA_, "15360")            \
        DSR(bv[0],  blkA_, "0")     DSR(bv[1],  blkA_, "1024")             \
        DSR(bv[2],  blkA_, "2048")  DSR(bv[3],  blkA_, "3072")             \
        DSR(bv[4],  blkA_, "4096")  DSR(bv[5],  blkA_, "5120")             \
        DSR(bv[6],  blkA_, "6144")  DSR(bv[7],  blkA_, "7168")             \
        DSR(bv[8],  blkA_, "8192")  DSR(bv[9],  blkA_, "9216")             \
        DSR(bv[10], blkA_, "10240") DSR(bv[11], blkA_, "11264")            \
        DSR(bv[12], blkA_, "12288") DSR(bv[13], blkA_, "13312")            \
        DSR(bv[14], blkA_, "14336") DSR(bv[15], blkA_, "15360")            \
        asm volatile("s_waitcnt lgkmcnt(0)" ::: "memory");                 \
        __builtin_amdgcn_sched_barrier(0);                                 \
        f2* dst_ = &pk[cp_ & 1][0][lane];                                  \
        _Pragma("unroll")                                                  \
        for (int i = 0; i < CH; ++i) {                                     \
            f2 t_; t_.x = lv[i]; t_.y = bv[i];                             \
            dst_[i * 64] = t_;                                             \
        }                                                                  \
    }

// Producer end-of-iteration: flush pack writes, then rendezvous.
#define FLUSHBAR()                                                         \
    asm volatile("s_waitcnt lgkmcnt(0)" ::: "memory");                     \
    __builtin_amdgcn_sched_barrier(0);                                     \
    __builtin_amdgcn_s_barrier();

// Consumer: read chunk cc's 16 packed float2 (conflict-free b64).
#define READPK(cc)                                                         \
    {                                                                      \
        const unsigned pA_ = (unsigned)(size_t)                            \
            (__attribute__((address_space(3))) void*)                      \
            &pk[(cc) & 1][0][lane];                                        \
        DSR64(lb[0],  pA_, "0")    DSR64(lb[1],  pA_, "512")               \
        DSR64(lb[2],  pA_, "1024") DSR64(lb[3],  pA_, "1536")              \
        DSR64(lb[4],  pA_, "2048") DSR64(lb[5],  pA_, "2560")              \
        DSR64(lb[6],  pA_, "3072") DSR64(lb[7],  pA_, "3584")              \
        DSR64(lb[8],  pA_, "4096") DSR64(lb[9],  pA_, "4608")              \
        DSR64(lb[10], pA_, "5120") DSR64(lb[11], pA_, "5632")              \
        DSR64(lb[12], pA_, "6144") DSR64(lb[13], pA_, "6656")              \
        DSR64(lb[14], pA_, "7168") DSR64(lb[15], pA_, "7680")              \
        asm volatile("s_waitcnt lgkmcnt(0)" ::: "memory");                 \
        __builtin_amdgcn_sched_barrier(0);                                 \
    }

// NSTEPS recurrence steps; lb[i].x = label prob, lb[i].y = blank prob.
// t = 1 + cc*CH + i; (t & 7) == 0 iff ((1 + i) & 7) == 0.
#define COMP_CHUNK(NSTEPS)                                                 \
    {                                                                      \
        _Pragma("unroll")                                                  \
        for (int i = 0; i < (NSTEPS); ++i) {                               \
            const float pb = lb[i].y + EPSF;                               \
            const float pl = lb[i].x + EPSF;                               \
            const float po = dpp_wave_shr1(a_odd);                         \
            const float skp = skip_ok ? po : 0.f;                          \
            const float ne = (a_even + po) * pb;                           \
            const float no = (a_odd + a_even + skp) * pl;                  \
            const float nt = (a_top + a_odd) * pb;                         \
            a_even = ne; a_odd = no; a_top = nt;                           \
            if (((1 + i) & 7) == 0) RESCALE();                             \
        }                                                                  \
    }

__global__ __launch_bounds__(128) void ctc_kernel(const int* __restrict__ y_true,
                                                  const float* __restrict__ y_pred,
                                                  float* __restrict__ out) {
    __shared__ float rows[NBUF][CH][C];  // 64 KB row ring
    __shared__ f2 pk[2][CH][64];         // 16 KB packed {lab, blk}
    const int b = blockIdx.x;
    const int tid = threadIdx.x;
    const int lane = tid & 63;
    const int wid = tid >> 6;
    const int label = y_true[b * U + lane];
    const float* __restrict__ rowp = y_pred + (size_t)b * (T * C);

    if (wid == 1) {
        // ---------------- producer wave ----------------
        float lv[CH], bv[CH];
        STAGE(0);
        STAGE(1);
        STAGE(2);
        // Iters 0..29: chunks c, c+1, c+2 outstanding (48 loads);
        // vmcnt(32) => chunk c landed. STAGE(c+3) refills to 48 (<= 63 cap).
        for (int c = 0; c < 30; ++c) {
            asm volatile("s_waitcnt vmcnt(32)" ::: "memory");
            __builtin_amdgcn_sched_barrier(0);
            PACK(c);
            if (c <= 28) STAGE(c + 3);
            FLUSHBAR();
        }
        // c = 30: outstanding 30,31 (32) -> vmcnt(16).
        asm volatile("s_waitcnt vmcnt(16)" ::: "memory");
        __builtin_amdgcn_sched_barrier(0);
        PACK(30);
        FLUSHBAR();
        // c = 31: outstanding 31 (16) -> vmcnt(0).
        asm volatile("s_waitcnt vmcnt(0)" ::: "memory");
        __builtin_amdgcn_sched_barrier(0);
        PACK(31);
        FLUSHBAR();
        // c = 32: barrier only (consumer computes chunk 31).
        __builtin_amdgcn_s_barrier();
    } else {
        // ---------------- consumer wave ----------------
        const int label_prev = __shfl_up(label, 1);
        const bool skip_ok = (lane > 0) && (label != label_prev);

        // t = 0 init (linear domain; unreachable states = 0).
        float a_even, a_odd, a_top;
        {
            const float pb = rowp[C - 1] + EPSF;
            const float pl = rowp[label] + EPSF;
            a_even = (lane == 0) ? pb : 0.f;
            a_odd  = (lane == 0) ? pl : 0.f;
            a_top  = 0.f;
        }
        int esum = 0;  // stored = true * 2^esum

        f2 lb[CH];
        __builtin_amdgcn_s_barrier();  // iter 0: nothing to compute yet
        for (int cc = 0; cc < 31; ++cc) {
            READPK(cc);
            COMP_CHUNK(CH);
            __builtin_amdgcn_s_barrier();
        }
        // chunk 31: t = 497..511 -> 15 steps.
        READPK(31);
        COMP_CHUNK(CH - 1);
        __builtin_amdgcn_s_barrier();

        // loss = -ln(alpha[128] + alpha[127]); true = stored * 2^-esum
        if (lane == 63)
            out[b] = -logf(a_top + a_odd) + (float)esum * 0.69314718055994531f;
    }
}

extern "C" void kernel_launch(void* const* d_in, const int* in_sizes, int n_in,
                              void* d_out, int out_size, void* d_ws, size_t ws_size,
                              hipStream_t stream) {
    const int* y_true   = (const int*)d_in[0];
    const float* y_pred = (const float*)d_in[1];
    float* out = (float*)d_out;
    hipLaunchKernelGGL(ctc_kernel, dim3(B), dim3(128), 0, stream,
                       y_true, y_pred, out);
}